// Round 11
// baseline (64.052 us; speedup 1.0000x reference)
//
#include <hip/hip_runtime.h>

// ---------------------------------------------------------------------------
// SelfAttentionRPR: B=8, T=1024, D=128, K=64, DEPTH=1, fp32 in/out.
// R11: R10 with the W1-prefetch bug fixed (4x8KB GLDS, was 2 -> half of W1
// missing -> absmax 11.6). 2 kernels + counter memset; manual device-scope
// grid barrier (vmcnt(0) drain -> block barrier -> thread0 ACQ_REL
// atomicAdd + spin + ACQUIRE -> block barrier).
//  prep_all:  5 W^T images + pe_key/pe_value images (pre-swizzled).
//  fused_all: Phase A: fc0+Q/K/V (counted-vmcnt W pipeline; Q -> LDS tile;
//             K/V -> swizzled images).  [manual grid barrier]
//             Phase B: 36-chunk global_load_lds stream attention + fused
//             C@W1+b1 tail. Q fragments come from LDS (no q16 round-trip).
// ---------------------------------------------------------------------------

#define TT 1024
#define DD 128
#define NB 8
#define SJH 1160         // S row stride (f16)

typedef _Float16 f16;
typedef __attribute__((ext_vector_type(8))) _Float16 f16x8;
typedef __attribute__((ext_vector_type(4))) _Float16 f16x4;
typedef __attribute__((ext_vector_type(4))) float f32x4;

static __device__ inline float fast_tanh(float x) {
    float xc = fminf(fmaxf(x, -12.f), 12.f);
    float e = __expf(2.f * xc);
    return (e - 1.f) / (e + 1.f);
}

#define GLDS(gp, lp) __builtin_amdgcn_global_load_lds( \
    (const __attribute__((address_space(1))) unsigned*)(gp), \
    (__attribute__((address_space(3))) unsigned*)(lp), 16, 0, 0)

// ---------------------------------------------------------------------------
// prep_all: blk 0..4 -> W^T images; blk 5 -> pe_key image; blk 6 -> pe_value.
// ---------------------------------------------------------------------------
__global__ __launch_bounds__(256) void prep_all(
        const float* __restrict__ W0, const float* __restrict__ Wq,
        const float* __restrict__ Wk, const float* __restrict__ Wv,
        const float* __restrict__ W1, const float* __restrict__ PEK,
        const float* __restrict__ PEV, char* __restrict__ wimg,
        char* __restrict__ pekimg, char* __restrict__ pevimg) {
    const int blk = blockIdx.x, t = threadIdx.x;
    if (blk < 5) {
        const float* W = blk == 0 ? W0 : blk == 1 ? Wq : blk == 2 ? Wk
                       : blk == 3 ? Wv : W1;
        char* o = wimg + (size_t)blk * 32768;
        #pragma unroll
        for (int it = 0; it < 8; it++) {
            int item = t + 256 * it;
            int n = item & 127, k0 = (item >> 7) * 8;
            f16x8 h;
            #pragma unroll
            for (int e = 0; e < 8; e++) h[e] = (f16)W[(k0 + e) * 128 + n];
            *(f16x8*)(o + n * 256 + ((2 * k0) ^ ((n & 7) << 4))) = h;
        }
    } else if (blk == 5) {
        for (int it = 0; it < 64; it++) {
            int idx = t + 256 * it;
            int m = idx >> 7, d = idx & 127;
            *(f16*)(pekimg + (m >> 6) * 16384 + (m & 63) * 256
                    + ((2 * d) ^ ((m & 7) << 4))) = (f16)PEK[m * 128 + d];
        }
    } else {
        for (int it = 0; it < 64; it++) {
            int idx = t + 256 * it;
            int m = idx >> 7, d = idx & 127;
            *(f16*)(pevimg + (m >> 6) * 16384 + d * 128
                    + ((2 * (m & 63)) ^ ((d & 7) << 4))) = (f16)PEV[m * 128 + d];
        }
    }
}

// ---------------------------------------------------------------------------
#define ISSUEW(wi, dst) do { \
    const char* _g = wimg + (size_t)(wi) * 32768 + t * 16; \
    char* _d = (dst) + t * 16; \
    _Pragma("unroll") for (int _i = 0; _i < 4; _i++) \
        GLDS(_g + _i * 8192, _d + _i * 8192); \
} while (0)

#define WAITN(N) do { \
    asm volatile("s_waitcnt vmcnt(" #N ") lgkmcnt(0)" ::: "memory"); \
    __builtin_amdgcn_s_barrier(); \
    __builtin_amdgcn_sched_barrier(0); \
} while (0)

// 8-wave GEMM core: wave = (it = wv&1 row-half, nq = wv>>1 col-quarter).
#define GEMM8(SRC, WL) do { \
    _Pragma("unroll") for (int _c = 0; _c < 4; _c++) { \
        int _ar = it * 16 + lr; \
        int _aa = (_ar << 8) + (_c << 6) + (lg << 4); \
        f16x8 _af = *(const f16x8*)((SRC) + (_aa ^ ((_ar & 7) << 4))); \
        _Pragma("unroll") for (int _nt = 0; _nt < 2; _nt++) { \
            int _n = nq * 32 + _nt * 16 + lr; \
            int _ba = (_n << 8) + (_c << 6) + (lg << 4); \
            f16x8 _bf = *(const f16x8*)((WL) + (_ba ^ ((_n & 7) << 4))); \
            acc[_nt] = __builtin_amdgcn_mfma_f32_16x16x32_f16( \
                    _af, _bf, acc[_nt], 0, 0, 0); \
        } } } while (0)

#define ISSUE16(src, bi) do { const char* _g = (src) + t * 16; \
    char* _d = BUF + (size_t)(bi) * 16384 + t * 16; \
    GLDS(_g, _d); \
    GLDS(_g + 8192, _d + 8192); \
} while (0)

__global__ __launch_bounds__(512) void fused_all(
        const float* __restrict__ x, const char* __restrict__ wimg,
        const float* __restrict__ b0v, const float* __restrict__ bqv,
        const float* __restrict__ bkv, const float* __restrict__ bvv,
        const float* __restrict__ PEK, const float* __restrict__ PEV,
        char* __restrict__ kimg, char* __restrict__ vimg,
        const char* __restrict__ pekimg, const char* __restrict__ pevimg,
        const float* __restrict__ b1, unsigned* __restrict__ syncc,
        float* __restrict__ out) {
    extern __shared__ __align__(16) char sm[];
    const int t = threadIdx.x, wv = t >> 6, l = t & 63;
    const int lr = l & 15, lg = l >> 4;
    const int blk = blockIdx.x;
    const int b = blk & 7, slice = blk >> 3;
    const int r0 = b * 1024 + slice * 32;
    const int it = wv & 1, nq = wv >> 1;

    // =================== Phase A: fc0 + Q/K/V ===================
    char* xs   = sm;              // 8KB (later ts)
    char* hsl  = sm + 8192;       // 8KB
    char* wA   = sm + 16384;      // 32KB
    char* wB   = sm + 49152;      // 32KB
    char* wC   = sm + 81920;      // 32KB
    char* qlds = sm + 139776;     // 8KB swizzled Q tile (survives barrier)

    ISSUEW(0, wA);
    ISSUEW(1, wB);
    {   // stage x (fp32 -> f16, swizzled [i][k])
        const float* X = x + (size_t)r0 * 128 + t * 8;
        f32x4 a0 = *(const f32x4*)X;
        f32x4 a1 = *(const f32x4*)(X + 4);
        f16x8 h;
        h[0]=(f16)a0[0]; h[1]=(f16)a0[1]; h[2]=(f16)a0[2]; h[3]=(f16)a0[3];
        h[4]=(f16)a1[0]; h[5]=(f16)a1[1]; h[6]=(f16)a1[2]; h[7]=(f16)a1[3];
        int a = t * 16;
        *(f16x8*)(xs + (a ^ (((a >> 8) & 7) << 4))) = h;
    }
    WAITN(4);                                    // W0 done; W1 in flight

    f32x4 acc[2];
    acc[0] = (f32x4){0,0,0,0}; acc[1] = (f32x4){0,0,0,0};
    GEMM8(xs, wA);                               // hs = relu(x@W0+b0)
    #pragma unroll
    for (int nt = 0; nt < 2; nt++) {
        int n = nq * 32 + nt * 16 + lr;
        float bb = b0v[n];
        #pragma unroll
        for (int r = 0; r < 4; r++) {
            int i = it * 16 + lg * 4 + r;
            float v = fmaxf(acc[nt][r] + bb, 0.f);
            int a = i * 256 + 2 * n;
            *(f16*)(hsl + (a ^ ((i & 7) << 4))) = (f16)v;
        }
    }
    ISSUEW(2, wC);
    WAITN(4);                                    // W1 done; W2 in flight

    acc[0] = (f32x4){0,0,0,0}; acc[1] = (f32x4){0,0,0,0};
    GEMM8(hsl, wB);                              // q = tanh(hs@Wq+bq) -> qlds
    #pragma unroll
    for (int nt = 0; nt < 2; nt++) {
        int n = nq * 32 + nt * 16 + lr;
        float bb = bqv[n];
        #pragma unroll
        for (int r = 0; r < 4; r++) {
            int i = it * 16 + lg * 4 + r;
            int a = i * 256 + 2 * n;
            *(f16*)(qlds + (a ^ ((i & 7) << 4))) =
                    (f16)fast_tanh(acc[nt][r] + bb);
        }
    }
    ISSUEW(3, wA);
    WAITN(4);                                    // W2 done; W3 in flight

    acc[0] = (f32x4){0,0,0,0}; acc[1] = (f32x4){0,0,0,0};
    GEMM8(hsl, wC);                              // k = tanh(hs@Wk+bk) -> ts
    f16* ts = (f16*)xs;
    #pragma unroll
    for (int nt = 0; nt < 2; nt++) {
        int n = nq * 32 + nt * 16 + lr;
        float bb = bkv[n];
        #pragma unroll
        for (int r = 0; r < 4; r++) {
            int i = it * 16 + lg * 4 + r;
            ts[i * 128 + n] = (f16)fast_tanh(acc[nt][r] + bb);
        }
    }
    asm volatile("s_waitcnt lgkmcnt(0)" ::: "memory");
    __builtin_amdgcn_s_barrier();
    __builtin_amdgcn_sched_barrier(0);
    {   // kimg f16x8 stores (16KB chunks: 64 rows x 256B)
        int row = t >> 4, seg = t & 15;
        int jg = r0 + row;
        int chunk = ((jg >> 10) << 4) + ((jg & 1023) >> 6);
        int jp = jg & 63;
        *(f16x8*)(kimg + (size_t)chunk * 16384 + jp * 256
                  + ((seg * 16) ^ ((jp & 7) << 4))) =
                *(const f16x8*)&ts[row * 128 + seg * 8];
    }
    WAITN(1);                                    // W3 landed (1 store pending)

    acc[0] = (f32x4){0,0,0,0}; acc[1] = (f32x4){0,0,0,0};
    GEMM8(hsl, wA);                              // v = tanh(hs@Wv+bv) -> vimg
    #pragma unroll
    for (int nt = 0; nt < 2; nt++) {
        int d = nq * 32 + nt * 16 + lr;
        float bb = bvv[d];
        f16x4 h;
        #pragma unroll
        for (int r = 0; r < 4; r++) h[r] = (f16)fast_tanh(acc[nt][r] + bb);
        int jb = r0 + it * 16 + lg * 4;
        int chunk = ((jb >> 10) << 4) + ((jb & 1023) >> 6);
        *(f16x4*)(vimg + (size_t)chunk * 16384 + d * 128
                  + ((2 * (jb & 63)) ^ ((d & 7) << 4))) = h;
    }

    // =================== manual grid barrier ===================
    asm volatile("s_waitcnt vmcnt(0) lgkmcnt(0)" ::: "memory");
    __syncthreads();                             // all waves' vm ops retired
    if (t == 0) {
        __threadfence();                         // release (L2 writeback)
        __hip_atomic_fetch_add(syncc, 1u, __ATOMIC_ACQ_REL,
                               __HIP_MEMORY_SCOPE_AGENT);
        while (__hip_atomic_load(syncc, __ATOMIC_RELAXED,
                                 __HIP_MEMORY_SCOPE_AGENT) < 256u)
            __builtin_amdgcn_s_sleep(2);
        (void)__hip_atomic_load(syncc, __ATOMIC_ACQUIRE,
                                __HIP_MEMORY_SCOPE_AGENT);   // acquire (inv)
    }
    __syncthreads();

    // =================== Phase B: attention + tail GEMM ===================
    f16*   S   = (f16*)sm;                       // 74240 B
    char*  BUF = sm + 74240;                     // 4 x 16384
    f16*   QB  = (f16*)(sm + 139776);            // 8448 B (reuses qlds space)
    float* LR  = (float*)(sm + 148224);          // 128 B

    const int i0 = slice << 5;
    const int it16 = (wv & 1) << 4;
    const int jsub = wv >> 1;

    // Q fragments + phase-2 Q row from the LDS Q tile (before QB overwrites)
    f16x8 qf[4];
    #pragma unroll
    for (int c = 0; c < 4; c++) {
        int row = it16 + lr;
        int a = row * 256 + c * 64 + lg * 16;
        qf[c] = *(const f16x8*)(qlds + (a ^ ((row & 7) << 4)));
    }
    const int row2 = t >> 4, l16 = t & 15;
    f16x8 qpv;
    {
        int a = row2 * 256 + l16 * 16;
        qpv = *(const f16x8*)(qlds + (a ^ ((row2 & 7) << 4)));
    }
    f32x4 pkv0 = *(const f32x4*)(PEK + 128 * 128 + l16 * 8);
    f32x4 pkv1 = *(const f32x4*)(PEK + 128 * 128 + l16 * 8 + 4);
    f32x4 pvr4 = *(const f32x4*)(PEV + 128 * 128 + wv * 16 + lg * 4);
    const float bb1 = b1[wv * 16 + lr];

    const char* kbase = kimg + (size_t)b * 16 * 16384;
    const char* vbase = vimg + (size_t)b * 16 * 16384;

    // barrier so all qlds reads complete before QB region reuse
    asm volatile("s_waitcnt lgkmcnt(0)" ::: "memory");
    __builtin_amdgcn_s_barrier();

    // prologue: chunks 0,1,2
    ISSUE16(kbase, 0);
    ISSUE16(kbase + 16384, 1);
    ISSUE16(kbase + 2 * 16384, 2);

    // ---------------- Phase 1: extended QK -> S ----------------
    for (int ch = 0; ch < 18; ch++) {
        asm volatile("s_waitcnt vmcnt(4)" ::: "memory");
        __builtin_amdgcn_s_barrier();
        __builtin_amdgcn_sched_barrier(0);
        {
            int ci = ch + 3;                     // 3..20 (>=18 -> V prefetch)
            const char* src = ci < 16 ? kbase + (size_t)ci * 16384
                            : (ci < 18 ? pekimg + (size_t)(ci - 16) * 16384
                                       : vbase + (size_t)(ci - 18) * 16384);
            ISSUE16(src, ci & 3);
        }
        const char* kb = BUF + (size_t)(ch & 3) * 16384;
        const int jp = jsub * 16 + lr;
        f32x4 a2 = {0.f, 0.f, 0.f, 0.f};
        #pragma unroll
        for (int c = 0; c < 4; c++) {
            f16x8 kf = *(const f16x8*)(kb + jp * 256
                        + ((c * 64 + lg * 16) ^ ((jp & 7) << 4)));
            a2 = __builtin_amdgcn_mfma_f32_16x16x32_f16(kf, qf[c], a2, 0, 0, 0);
        }
        f16x4 h = {(f16)a2[0], (f16)a2[1], (f16)a2[2], (f16)a2[3]};
        *(f16x4*)&S[(it16 + lr) * SJH + ch * 64 + jsub * 16 + lg * 4] = h;
    }
    asm volatile("s_waitcnt lgkmcnt(0)" ::: "memory");
    __builtin_amdgcn_s_barrier();
    __builtin_amdgcn_sched_barrier(0);

    // ---------------- Phase 2: softmax + buckets (row = t>>4) ----------------
    {
        const int ig = i0 + row2;
        f16* srow = S + row2 * SJH;
        f16* qrow = QB + row2 * 132;

        float qp;   // qpe[row][128] = Q[row] . pe_key[128]
        {
            float s = 0.f;
            #pragma unroll
            for (int e = 0; e < 4; e++) s += (float)qpv[e] * pkv0[e];
            #pragma unroll
            for (int e = 0; e < 4; e++) s += (float)qpv[e + 4] * pkv1[e];
            #pragma unroll
            for (int off = 8; off; off >>= 1) s += __shfl_xor(s, off, 64);
            qp = s;
        }
        for (int mm = l16; mm < 128; mm += 16) {   // qpe S->QB, zero buckets
            qrow[mm] = srow[1024 + mm];
            srow[1024 + mm] = (f16)0.f;
        }
        if (l16 == 0) qrow[128] = (f16)qp;
        const float qlo = (float)qrow[0], qhi = qp;

        float lmax = -3.0e38f;
        #pragma unroll
        for (int kk = 0; kk < 8; kk++) {
            int j0 = kk * 128 + l16 * 8;
            f16x8 sv = *(const f16x8*)(srow + j0);
            #pragma unroll
            for (int e = 0; e < 8; e++) {
                int idd = 64 + j0 + e - ig;
                float qv = (idd <= 0) ? qlo : (idd >= 128 ? qhi : (float)qrow[idd]);
                lmax = fmaxf(lmax, (float)sv[e] + qv);
            }
        }
        #pragma unroll
        for (int off = 8; off; off >>= 1) lmax = fmaxf(lmax, __shfl_xor(lmax, off, 64));

        float lsum = 0.f, s0 = 0.f, s1 = 0.f;
        #pragma unroll
        for (int kk = 0; kk < 8; kk++) {
            int j0 = kk * 128 + l16 * 8;
            f16x8 sv = *(const f16x8*)(srow + j0);
            f16x8 pv;
            #pragma unroll
            for (int e = 0; e < 8; e++) {
                int idd = 64 + j0 + e - ig;
                float qv = (idd <= 0) ? qlo : (idd >= 128 ? qhi : (float)qrow[idd]);
                float p = __expf((float)sv[e] + qv - lmax);
                pv[e] = (f16)p;
                lsum += p;
                if (idd <= 0)        s0 += p;
                else if (idd >= 128) s1 += p;
                else                 srow[1024 + idd] = (f16)p;   // band bucket
            }
            *(f16x8*)(srow + j0) = pv;          // unnormalized P
        }
        #pragma unroll
        for (int off = 8; off; off >>= 1) {
            lsum += __shfl_xor(lsum, off, 64);
            s0   += __shfl_xor(s0,   off, 64);
            s1   += __shfl_xor(s1,   off, 64);
        }
        if (l16 == 0) {
            srow[1024] = (f16)s0;
            srow[1152] = (f16)s1;
            LR[row2] = lsum;
        }
    }
    asm volatile("s_waitcnt lgkmcnt(0)" ::: "memory");
    __builtin_amdgcn_s_barrier();
    __builtin_amdgcn_sched_barrier(0);

    // ---------------- Phase 3: C^T = V'^T . P'^T ----------------
    f32x4 cacc[2] = {};
    for (int ch = 0; ch < 18; ch++) {
        if (ch <= 15)      asm volatile("s_waitcnt vmcnt(4)" ::: "memory");
        else if (ch == 16) asm volatile("s_waitcnt vmcnt(2)" ::: "memory");
        else               asm volatile("s_waitcnt vmcnt(0)" ::: "memory");
        __builtin_amdgcn_s_barrier();
        __builtin_amdgcn_sched_barrier(0);
        if (ch < 15) {
            int ci = ch + 3;
            const char* src = ci < 16 ? vbase + (size_t)ci * 16384
                                      : pevimg + (size_t)(ci - 16) * 16384;
            ISSUE16(src, (ci + 2) & 3);
        } else if (ch == 17) {
            const char* _g = wimg + 4 * 32768 + t * 16;   // W1 image (32KB)
            char* _d = BUF + t * 16;
            #pragma unroll
            for (int _i = 0; _i < 4; _i++)
                GLDS(_g + _i * 8192, _d + _i * 8192);
        }
        const char* vb = BUF + (size_t)((ch + 2) & 3) * 16384;
        const int dp = wv * 16 + lr;
        #pragma unroll
        for (int c2 = 0; c2 < 2; c2++) {
            f16x8 vf = *(const f16x8*)(vb + dp * 128
                        + ((c2 * 64 + lg * 16) ^ ((dp & 7) << 4)));
            #pragma unroll
            for (int i2 = 0; i2 < 2; i2++) {
                f16x8 pf = *(const f16x8*)&S[(i2 * 16 + lr) * SJH
                            + ch * 64 + c2 * 32 + lg * 8];
                cacc[i2] = __builtin_amdgcn_mfma_f32_16x16x32_f16(vf, pf, cacc[i2], 0, 0, 0);
            }
        }
    }

    // ---- epilogue: + w[128]*pe_value[128], normalize -> c-tile in LDS ----
    float w128[2], rden[2];
    #pragma unroll
    for (int i2 = 0; i2 < 2; i2++) {
        int irow = i2 * 16 + lr;
        w128[i2] = (float)S[irow * SJH + 1152];
        rden[i2] = 1.f / LR[irow];
    }
    asm volatile("s_waitcnt lgkmcnt(0)" ::: "memory");
    __builtin_amdgcn_s_barrier();                        // all S reads done
    __builtin_amdgcn_sched_barrier(0);
    char* cl = (char*)S;                                 // c-tile [i][d] swizzled
    #pragma unroll
    for (int i2 = 0; i2 < 2; i2++) {
        int i = i2 * 16 + lr;
        #pragma unroll
        for (int r = 0; r < 4; r++) {
            int d = wv * 16 + lg * 4 + r;
            float cv = (cacc[i2][r] + w128[i2] * pvr4[r]) * rden[i2];
            int a = i * 256 + 2 * d;
            *(f16*)(cl + (a ^ ((i & 7) << 4))) = (f16)cv;
        }
    }
    asm volatile("s_waitcnt vmcnt(0) lgkmcnt(0)" ::: "memory");
    __builtin_amdgcn_s_barrier();                        // W1 landed, cl visible
    __builtin_amdgcn_sched_barrier(0);

    // ---- tail GEMM: out = relu(c @ W1 + b1), fp32 ----
    const char* wl4 = BUF;
    f32x4 oacc[2] = {};
    #pragma unroll
    for (int c = 0; c < 4; c++) {
        f16x8 af[2], bf;
        #pragma unroll
        for (int i2 = 0; i2 < 2; i2++) {
            int row = i2 * 16 + lr;
            int a = (row << 8) + (c << 6) + (lg << 4);
            af[i2] = *(const f16x8*)(cl + (a ^ ((row & 7) << 4)));
        }
        {
            int n = wv * 16 + lr;
            int a = (n << 8) + (c << 6) + (lg << 4);
            bf = *(const f16x8*)(wl4 + (a ^ ((n & 7) << 4)));
        }
        #pragma unroll
        for (int i2 = 0; i2 < 2; i2++)
            oacc[i2] = __builtin_amdgcn_mfma_f32_16x16x32_f16(af[i2], bf, oacc[i2], 0, 0, 0);
    }
    {
        int n = wv * 16 + lr;
        #pragma unroll
        for (int i2 = 0; i2 < 2; i2++) {
            #pragma unroll
            for (int r = 0; r < 4; r++) {
                int i = i2 * 16 + lg * 4 + r;
                out[(size_t)(b * TT + i0 + i) * DD + n] = fmaxf(oacc[i2][r] + bb1, 0.f);
            }
        }
    }
}

// ---------------------------------------------------------------------------

extern "C" void kernel_launch(void* const* d_in, const int* in_sizes, int n_in,
                              void* d_out, int out_size, void* d_ws, size_t ws_size,
                              hipStream_t stream) {
    const float* x   = (const float*)d_in[0];
    const float* W0  = (const float*)d_in[1];
    const float* b0  = (const float*)d_in[2];
    const float* Wq  = (const float*)d_in[3];
    const float* bq  = (const float*)d_in[4];
    const float* Wk  = (const float*)d_in[5];
    const float* bk  = (const float*)d_in[6];
    const float* Wv  = (const float*)d_in[7];
    const float* bv  = (const float*)d_in[8];
    const float* W1  = (const float*)d_in[9];
    const float* b1  = (const float*)d_in[10];
    const float* pek = (const float*)d_in[11];
    const float* pev = (const float*)d_in[12];
    float* out = (float*)d_out;

    char* wimg   = (char*)d_ws;                     // 5 x 32KB
    char* kimg   = wimg + 5 * 32768;                // 128 x 16KB = 2 MB
    char* vimg   = kimg + (size_t)128 * 16384;      // 2 MB
    char* pekimg = vimg + (size_t)128 * 16384;      // 32 KB
    char* pevimg = pekimg + 32768;                  // 32 KB
    unsigned* syncc = (unsigned*)(pevimg + 32768);  // 4 B barrier counter

    const int SMEM = 148352;
    hipFuncSetAttribute(reinterpret_cast<const void*>(fused_all),
                        hipFuncAttributeMaxDynamicSharedMemorySize, SMEM);

    hipMemsetAsync(syncc, 0, sizeof(unsigned), stream);
    hipLaunchKernelGGL(prep_all, dim3(7), dim3(256), 0, stream,
                       W0, Wq, Wk, Wv, W1, pek, pev, wimg, pekimg, pevimg);
    hipLaunchKernelGGL(fused_all, dim3(256), dim3(512), SMEM, stream,
                       x, wimg, b0, bq, bk, bv, pek, pev, kimg, vimg,
                       pekimg, pevimg, b1, syncc, out);
}

// Round 12
// 50.758 us; speedup vs baseline: 1.2619x; 1.2619x over previous
//
#include <hip/hip_runtime.h>

// ---------------------------------------------------------------------------
// SelfAttentionRPR: B=8, T=1024, D=128, K=64, DEPTH=1, fp32 in/out.
// R12: 3 kernels (fusion reverted — 1 block/CU starved the CU; R11 post-mortem).
//  prep_all:  5 W^T images + pe_key/pe_value images (pre-swizzled).
//  fused_qkv: R8's proven fc0+Q/K/V chain (3 W buffers, counted vmcnt(8),
//             XCD-aligned block remap), 256 blocks x 256 thr.
//  attn_all:  REBUILT for 2 blocks/CU: 512 blocks x 256 thr, 16 Q-rows,
//             74KB LDS (S 37K + 2x16K chunk buffers + QB). Depth-1 chunk
//             stream per block; cross-block overlap hides latency (m114).
//             Fused C@W1+b1 tail (W1 staged in two 16KB steps).
// ---------------------------------------------------------------------------

#define TT 1024
#define DD 128
#define NB 8
#define SJH 1160         // S row stride (f16)

typedef _Float16 f16;
typedef __attribute__((ext_vector_type(8))) _Float16 f16x8;
typedef __attribute__((ext_vector_type(4))) _Float16 f16x4;
typedef __attribute__((ext_vector_type(4))) float f32x4;

static __device__ inline float fast_tanh(float x) {
    float xc = fminf(fmaxf(x, -12.f), 12.f);
    float e = __expf(2.f * xc);
    return (e - 1.f) / (e + 1.f);
}

#define GLDS(gp, lp) __builtin_amdgcn_global_load_lds( \
    (const __attribute__((address_space(1))) unsigned*)(gp), \
    (__attribute__((address_space(3))) unsigned*)(lp), 16, 0, 0)

// ---------------------------------------------------------------------------
// prep_all: blk 0..4 -> W^T images; blk 5 -> pe_key image; blk 6 -> pe_value.
// ---------------------------------------------------------------------------
__global__ __launch_bounds__(256) void prep_all(
        const float* __restrict__ W0, const float* __restrict__ Wq,
        const float* __restrict__ Wk, const float* __restrict__ Wv,
        const float* __restrict__ W1, const float* __restrict__ PEK,
        const float* __restrict__ PEV, char* __restrict__ wimg,
        char* __restrict__ pekimg, char* __restrict__ pevimg) {
    const int blk = blockIdx.x, t = threadIdx.x;
    if (blk < 5) {
        const float* W = blk == 0 ? W0 : blk == 1 ? Wq : blk == 2 ? Wk
                       : blk == 3 ? Wv : W1;
        char* o = wimg + (size_t)blk * 32768;
        #pragma unroll
        for (int it = 0; it < 8; it++) {
            int item = t + 256 * it;
            int n = item & 127, k0 = (item >> 7) * 8;
            f16x8 h;
            #pragma unroll
            for (int e = 0; e < 8; e++) h[e] = (f16)W[(k0 + e) * 128 + n];
            *(f16x8*)(o + n * 256 + ((2 * k0) ^ ((n & 7) << 4))) = h;
        }
    } else if (blk == 5) {
        for (int it = 0; it < 64; it++) {
            int idx = t + 256 * it;
            int m = idx >> 7, d = idx & 127;
            *(f16*)(pekimg + (m >> 6) * 16384 + (m & 63) * 256
                    + ((2 * d) ^ ((m & 7) << 4))) = (f16)PEK[m * 128 + d];
        }
    } else {
        for (int it = 0; it < 64; it++) {
            int idx = t + 256 * it;
            int m = idx >> 7, d = idx & 127;
            *(f16*)(pevimg + (m >> 6) * 16384 + d * 128
                    + ((2 * (m & 63)) ^ ((d & 7) << 4))) = (f16)PEV[m * 128 + d];
        }
    }
}

// ---------------------------------------------------------------------------
#define ZACC() do { _Pragma("unroll") for (int _i = 0; _i < 2; _i++) \
    _Pragma("unroll") for (int _j = 0; _j < 2; _j++) \
        acc[_i][_j] = (f32x4){0.f, 0.f, 0.f, 0.f}; } while (0)

#define GEMMCORE(SRC, WL) do { \
    _Pragma("unroll") for (int _c = 0; _c < 4; _c++) { \
        f16x8 _af[2], _bf[2]; \
        _Pragma("unroll") for (int _it = 0; _it < 2; _it++) { \
            int _row = _it * 16 + (l & 15); \
            int _a = (_row << 8) + (_c << 6) + ((l >> 4) << 4); \
            _af[_it] = *(const f16x8*)((SRC) + (_a ^ ((_row & 7) << 4))); } \
        _Pragma("unroll") for (int _nt = 0; _nt < 2; _nt++) { \
            int _n = wv * 32 + _nt * 16 + (l & 15); \
            int _a = (_n << 8) + (_c << 6) + ((l >> 4) << 4); \
            _bf[_nt] = *(const f16x8*)((WL) + (_a ^ ((_n & 7) << 4))); } \
        _Pragma("unroll") for (int _it = 0; _it < 2; _it++) \
        _Pragma("unroll") for (int _nt = 0; _nt < 2; _nt++) \
            acc[_it][_nt] = __builtin_amdgcn_mfma_f32_16x16x32_f16( \
                    _af[_it], _bf[_nt], acc[_it][_nt], 0, 0, 0); } } while (0)

#define ISSUEW(wi, dst) do { \
    const char* _g = wimg + (size_t)(wi) * 32768 + t * 16; \
    char* _d = (dst) + t * 16; \
    _Pragma("unroll") for (int _i = 0; _i < 8; _i++) \
        GLDS(_g + _i * 4096, _d + _i * 4096); \
} while (0)

#define WAITBAR(N) do { \
    asm volatile("s_waitcnt vmcnt(" #N ") lgkmcnt(0)" ::: "memory"); \
    __builtin_amdgcn_s_barrier(); \
    __builtin_amdgcn_sched_barrier(0); \
} while (0)

// fused_qkv: blocks 0..255 -> (b = blk&7, slice = blk>>3): rows b*1024+slice*32
__global__ __launch_bounds__(256) void fused_qkv(
        const float* __restrict__ x, const char* __restrict__ wimg,
        const float* __restrict__ b0, const float* __restrict__ bq,
        const float* __restrict__ bk, const float* __restrict__ bv,
        f16* __restrict__ q16, char* __restrict__ kimg,
        char* __restrict__ vimg) {
    extern __shared__ __align__(16) char smq[];
    char* xs  = smq;            // 8KB  x-tile (later ts)
    char* hsl = smq + 8192;     // 8KB  hs-tile
    char* wA  = smq + 16384;    // 32KB
    char* wB  = smq + 49152;    // 32KB
    char* wC  = smq + 81920;    // 32KB
    const int t = threadIdx.x, wv = t >> 6, l = t & 63;
    const int blk = blockIdx.x;

    const int r0 = (blk & 7) * 1024 + (blk >> 3) * 32;   // XCD-aligned rows
    ISSUEW(0, wA);
    ISSUEW(1, wB);
    {   // stage x (fp32 -> f16, swizzled)
        const float* X = x + (size_t)r0 * 128;
        #pragma unroll
        for (int i = 0; i < 2; i++) {
            f32x4 a0 = *(const f32x4*)(X + t * 16 + i * 8);
            f32x4 a1 = *(const f32x4*)(X + t * 16 + i * 8 + 4);
            f16x8 h;
            h[0]=(f16)a0[0]; h[1]=(f16)a0[1]; h[2]=(f16)a0[2]; h[3]=(f16)a0[3];
            h[4]=(f16)a1[0]; h[5]=(f16)a1[1]; h[6]=(f16)a1[2]; h[7]=(f16)a1[3];
            int a = t * 32 + i * 16;
            *(f16x8*)(xs + (a ^ (((a >> 8) & 7) << 4))) = h;
        }
    }
    WAITBAR(8);                                  // W0 landed; W1 in flight

    f32x4 acc[2][2];
    ZACC();
    GEMMCORE(xs, wA);                            // hs = relu(x@W0+b0)
    {
        #pragma unroll
        for (int it = 0; it < 2; it++)
            #pragma unroll
            for (int nt = 0; nt < 2; nt++) {
                int n = wv * 32 + nt * 16 + (l & 15);
                float bb = b0[n];
                #pragma unroll
                for (int r = 0; r < 4; r++) {
                    int i = it * 16 + (l >> 4) * 4 + r;
                    float v = fmaxf(acc[it][nt][r] + bb, 0.f);
                    int a = i * 256 + 2 * n;
                    *(f16*)(hsl + (a ^ ((i & 7) << 4))) = (f16)v;
                }
            }
    }
    ISSUEW(2, wC);
    WAITBAR(8);                                  // drains W1; W2 in flight

    ZACC();
    GEMMCORE(hsl, wB);                           // q = tanh(hs@Wq+bq)
    {
        #pragma unroll
        for (int it = 0; it < 2; it++)
            #pragma unroll
            for (int nt = 0; nt < 2; nt++) {
                int n = wv * 32 + nt * 16 + (l & 15);
                float bb = bq[n];
                #pragma unroll
                for (int r = 0; r < 4; r++) {
                    int i = it * 16 + (l >> 4) * 4 + r;
                    q16[(size_t)(r0 + i) * 128 + n] =
                            (f16)fast_tanh(acc[it][nt][r] + bb);
                }
            }
    }
    ISSUEW(3, wA);                               // Wv (W0 buffer free)
    WAITBAR(8);                                  // drains W2 + q stores; W3 in flight

    ZACC();
    GEMMCORE(hsl, wC);                           // k = tanh(hs@Wk+bk) -> ts
    f16* ts = (f16*)xs;
    {
        #pragma unroll
        for (int it = 0; it < 2; it++)
            #pragma unroll
            for (int nt = 0; nt < 2; nt++) {
                int n = wv * 32 + nt * 16 + (l & 15);
                float bb = bk[n];
                #pragma unroll
                for (int r = 0; r < 4; r++) {
                    int i = it * 16 + (l >> 4) * 4 + r;
                    ts[i * 128 + n] = (f16)fast_tanh(acc[it][nt][r] + bb);
                }
            }
    }
    WAITBAR(0);                                  // W3 landed; ts visible

    {   // kimg writes from ts (16KB chunks: 64 rows x 256B)
        #pragma unroll
        for (int half = 0; half < 2; half++) {
            int row = (t >> 4) + half * 16;
            int seg = t & 15;
            int jg = r0 + row;
            int chunk = ((jg >> 10) << 4) + ((jg & 1023) >> 6);
            int jp = jg & 63;
            char* dst = kimg + (size_t)chunk * 16384 + jp * 256
                      + ((seg * 16) ^ ((jp & 7) << 4));
            *(f16x8*)dst = *(const f16x8*)&ts[row * 128 + seg * 8];
        }
    }
    ZACC();
    GEMMCORE(hsl, wA);                           // v = tanh(hs@Wv+bv)
    {
        #pragma unroll
        for (int it = 0; it < 2; it++)
            #pragma unroll
            for (int nt = 0; nt < 2; nt++) {
                int d = wv * 32 + nt * 16 + (l & 15);
                float bb = bv[d];
                f16x4 h;
                #pragma unroll
                for (int r = 0; r < 4; r++)
                    h[r] = (f16)fast_tanh(acc[it][nt][r] + bb);
                int jb = r0 + it * 16 + ((l >> 4) << 2);
                int chunk = ((jb >> 10) << 4) + ((jb & 1023) >> 6);
                char* dst = vimg + (size_t)chunk * 16384 + d * 128
                          + ((2 * (jb & 63)) ^ ((d & 7) << 4));
                *(f16x4*)dst = h;
            }
    }
}

// ---------------------------------------------------------------------------
// attn_all: 512 blocks x 256 thr (4 waves), 16 Q-rows, 74KB LDS -> 2/CU.
// Depth-1 chunk stream: wait vmcnt(0) -> barrier -> issue ch+1 -> compute ch.
// ---------------------------------------------------------------------------
#define ISSUE16(src, bi) do { const char* _g = (src) + t * 16; \
    char* _d = BUF + (size_t)(bi) * 16384 + t * 16; \
    GLDS(_g, _d); GLDS(_g + 4096, _d + 4096); \
    GLDS(_g + 8192, _d + 8192); GLDS(_g + 12288, _d + 12288); \
} while (0)

__global__ __launch_bounds__(256) void attn_all(
        const f16* __restrict__ q16, const char* __restrict__ kimg,
        const char* __restrict__ pekimg, const char* __restrict__ vimg,
        const char* __restrict__ pevimg, const float* __restrict__ PEK,
        const float* __restrict__ PEV, const char* __restrict__ w1img,
        const float* __restrict__ b1, float* __restrict__ out) {
    extern __shared__ __align__(16) char sm7[];
    f16*   S   = (f16*)sm7;                              // 37120 B
    char*  BUF = sm7 + 37120;                            // 2 x 16384
    f16*   QB  = (f16*)(sm7 + 69888);                    // 4224 B
    float* LR  = (float*)(sm7 + 74112);                  // 64 B

    const int t = threadIdx.x, wv = t >> 6, l = t & 63;
    const int lr = l & 15, lg = l >> 4;
    const int b = blockIdx.x & 7;
    const int i0 = (blockIdx.x >> 3) << 4;

    // ---- register preloads (all global reads before chunk issues) ----
    f16x8 qf[4];
    {
        const f16* qb = q16 + (size_t)(b * TT + i0 + lr) * 128 + lg * 8;
        #pragma unroll
        for (int c = 0; c < 4; c++) qf[c] = *(const f16x8*)(qb + c * 32);
    }
    const int row2 = t >> 4, l16 = t & 15;
    f16x8 qpv = *(const f16x8*)(q16 + (size_t)(b * TT + i0 + row2) * 128 + l16 * 8);
    f32x4 pkv0 = *(const f32x4*)(PEK + 128 * 128 + l16 * 8);
    f32x4 pkv1 = *(const f32x4*)(PEK + 128 * 128 + l16 * 8 + 4);
    f32x4 pvr4[2];
    #pragma unroll
    for (int dt = 0; dt < 2; dt++)
        pvr4[dt] = *(const f32x4*)(PEV + 128 * 128 + wv * 32 + dt * 16 + lg * 4);
    float bb1[2];
    #pragma unroll
    for (int nt = 0; nt < 2; nt++) bb1[nt] = b1[wv * 32 + nt * 16 + lr];

    const char* kbase = kimg + (size_t)b * 16 * 16384;
    const char* vbase = vimg + (size_t)b * 16 * 16384;

    ISSUE16(kbase, 0);                                   // prologue: chunk 0

    // ---------------- Phase 1: extended QK -> S ----------------
    for (int ch = 0; ch < 18; ch++) {
        asm volatile("s_waitcnt vmcnt(0)" ::: "memory");
        __builtin_amdgcn_s_barrier();
        __builtin_amdgcn_sched_barrier(0);
        {
            int ci = ch + 1;                   // 18 -> prefetch V chunk 0
            const char* src = ci < 16 ? kbase + (size_t)ci * 16384
                            : (ci < 18 ? pekimg + (size_t)(ci - 16) * 16384
                                       : vbase);
            ISSUE16(src, ci & 1);
        }
        const char* kb = BUF + (size_t)(ch & 1) * 16384;
        const int jp = wv * 16 + lr;
        f32x4 a2 = {0.f, 0.f, 0.f, 0.f};
        #pragma unroll
        for (int c = 0; c < 4; c++) {
            f16x8 kf = *(const f16x8*)(kb + jp * 256
                        + ((c * 64 + lg * 16) ^ ((jp & 7) << 4)));
            a2 = __builtin_amdgcn_mfma_f32_16x16x32_f16(kf, qf[c], a2, 0, 0, 0);
        }
        f16x4 h = {(f16)a2[0], (f16)a2[1], (f16)a2[2], (f16)a2[3]};
        *(f16x4*)&S[lr * SJH + ch * 64 + wv * 16 + lg * 4] = h;
    }
    asm volatile("s_waitcnt lgkmcnt(0)" ::: "memory");
    __builtin_amdgcn_s_barrier();
    __builtin_amdgcn_sched_barrier(0);

    // ---------------- Phase 2: softmax + buckets (row = t>>4, 16 lanes) ------
    {
        const int ig = i0 + row2;
        f16* srow = S + row2 * SJH;
        f16* qrow = QB + row2 * 132;

        float qp;   // qpe[row][128] = Q[row] . pe_key[128]
        {
            float s = 0.f;
            #pragma unroll
            for (int e = 0; e < 4; e++) s += (float)qpv[e] * pkv0[e];
            #pragma unroll
            for (int e = 0; e < 4; e++) s += (float)qpv[e + 4] * pkv1[e];
            #pragma unroll
            for (int off = 8; off; off >>= 1) s += __shfl_xor(s, off, 64);
            qp = s;
        }
        for (int mm = l16; mm < 128; mm += 16) {   // qpe S->QB, zero buckets
            qrow[mm] = srow[1024 + mm];
            srow[1024 + mm] = (f16)0.f;
        }
        if (l16 == 0) qrow[128] = (f16)qp;
        const float qlo = (float)qrow[0], qhi = qp;

        float lmax = -3.0e38f;
        #pragma unroll
        for (int kk = 0; kk < 8; kk++) {
            int j0 = kk * 128 + l16 * 8;
            f16x8 sv = *(const f16x8*)(srow + j0);
            #pragma unroll
            for (int e = 0; e < 8; e++) {
                int idd = 64 + j0 + e - ig;
                float qv = (idd <= 0) ? qlo : (idd >= 128 ? qhi : (float)qrow[idd]);
                lmax = fmaxf(lmax, (float)sv[e] + qv);
            }
        }
        #pragma unroll
        for (int off = 8; off; off >>= 1) lmax = fmaxf(lmax, __shfl_xor(lmax, off, 64));

        float lsum = 0.f, s0 = 0.f, s1 = 0.f;
        #pragma unroll
        for (int kk = 0; kk < 8; kk++) {
            int j0 = kk * 128 + l16 * 8;
            f16x8 sv = *(const f16x8*)(srow + j0);
            f16x8 pv;
            #pragma unroll
            for (int e = 0; e < 8; e++) {
                int idd = 64 + j0 + e - ig;
                float qv = (idd <= 0) ? qlo : (idd >= 128 ? qhi : (float)qrow[idd]);
                float p = __expf((float)sv[e] + qv - lmax);
                pv[e] = (f16)p;
                lsum += p;
                if (idd <= 0)        s0 += p;
                else if (idd >= 128) s1 += p;
                else                 srow[1024 + idd] = (f16)p;   // band bucket
            }
            *(f16x8*)(srow + j0) = pv;          // unnormalized P
        }
        #pragma unroll
        for (int off = 8; off; off >>= 1) {
            lsum += __shfl_xor(lsum, off, 64);
            s0   += __shfl_xor(s0,   off, 64);
            s1   += __shfl_xor(s1,   off, 64);
        }
        if (l16 == 0) {
            srow[1024] = (f16)s0;
            srow[1152] = (f16)s1;
            LR[row2] = lsum;
        }
    }
    asm volatile("s_waitcnt lgkmcnt(0)" ::: "memory");
    __builtin_amdgcn_s_barrier();
    __builtin_amdgcn_sched_barrier(0);

    // ---------------- Phase 3: C^T = V'^T . P'^T ----------------
    f32x4 cacc[2] = {};
    for (int ch = 0; ch < 18; ch++) {
        asm volatile("s_waitcnt vmcnt(0)" ::: "memory");
        __builtin_amdgcn_s_barrier();
        __builtin_amdgcn_sched_barrier(0);
        {
            int ci = ch + 1;
            if (ci < 16)      ISSUE16(vbase + (size_t)ci * 16384, ci & 1);
            else if (ci < 18) ISSUE16(pevimg + (size_t)(ci - 16) * 16384, ci & 1);
            else {            // W1 first half -> buf0 (chunk 16 retired)
                const char* _g = w1img + t * 16;
                char* _d = BUF + t * 16;
                GLDS(_g, _d); GLDS(_g + 4096, _d + 4096);
                GLDS(_g + 8192, _d + 8192); GLDS(_g + 12288, _d + 12288);
            }
        }
        const char* vb = BUF + (size_t)(ch & 1) * 16384;
        #pragma unroll
        for (int c2 = 0; c2 < 2; c2++) {
            f16x8 pf = *(const f16x8*)&S[lr * SJH + ch * 64 + c2 * 32 + lg * 8];
            #pragma unroll
            for (int dt = 0; dt < 2; dt++) {
                int dp = wv * 32 + dt * 16 + lr;
                f16x8 vf = *(const f16x8*)(vb + dp * 128
                            + ((c2 * 64 + lg * 16) ^ ((dp & 7) << 4)));
                cacc[dt] = __builtin_amdgcn_mfma_f32_16x16x32_f16(vf, pf, cacc[dt], 0, 0, 0);
            }
        }
    }

    // ---- epilogue: + w[128]*pe_value[128], normalize -> c-tile in LDS ----
    const float w128 = (float)S[lr * SJH + 1152];
    const float rden = 1.f / LR[lr];
    asm volatile("s_waitcnt lgkmcnt(0)" ::: "memory");
    __builtin_amdgcn_s_barrier();                // S/buf1 reads all retired
    __builtin_amdgcn_sched_barrier(0);
    {   // W1 second half -> buf1
        const char* _g = w1img + 16384 + t * 16;
        char* _d = BUF + 16384 + t * 16;
        GLDS(_g, _d); GLDS(_g + 4096, _d + 4096);
        GLDS(_g + 8192, _d + 8192); GLDS(_g + 12288, _d + 12288);
    }
    char* cl = (char*)S;                         // c-tile [i][d] swizzled
    #pragma unroll
    for (int dt = 0; dt < 2; dt++) {
        #pragma unroll
        for (int r = 0; r < 4; r++) {
            int d = wv * 32 + dt * 16 + lg * 4 + r;
            float cv = (cacc[dt][r] + w128 * pvr4[dt][r]) * rden;
            int a = lr * 256 + 2 * d;
            *(f16*)(cl + (a ^ ((lr & 7) << 4))) = (f16)cv;
        }
    }
    asm volatile("s_waitcnt vmcnt(0) lgkmcnt(0)" ::: "memory");
    __builtin_amdgcn_s_barrier();                // W1 landed, cl visible
    __builtin_amdgcn_sched_barrier(0);

    // ---- tail GEMM: out = relu(c @ W1 + b1), fp32 ----
    const char* wl4 = BUF;
    f32x4 oacc[2] = {};
    #pragma unroll
    for (int c = 0; c < 4; c++) {
        int aa = lr * 256 + c * 64 + lg * 16;
        f16x8 af = *(const f16x8*)(cl + (aa ^ ((lr & 7) << 4)));
        #pragma unroll
        for (int nt = 0; nt < 2; nt++) {
            int n = wv * 32 + nt * 16 + lr;
            int ba = n * 256 + c * 64 + lg * 16;
            f16x8 bf = *(const f16x8*)(wl4 + (ba ^ ((n & 7) << 4)));
            oacc[nt] = __builtin_amdgcn_mfma_f32_16x16x32_f16(af, bf, oacc[nt], 0, 0, 0);
        }
    }
    #pragma unroll
    for (int nt = 0; nt < 2; nt++) {
        int n = wv * 32 + nt * 16 + lr;
        #pragma unroll
        for (int r = 0; r < 4; r++) {
            int i = lg * 4 + r;
            out[(size_t)(b * TT + i0 + i) * DD + n] = fmaxf(oacc[nt][r] + bb1[nt], 0.f);
        }
    }
}

// ---------------------------------------------------------------------------

extern "C" void kernel_launch(void* const* d_in, const int* in_sizes, int n_in,
                              void* d_out, int out_size, void* d_ws, size_t ws_size,
                              hipStream_t stream) {
    const float* x   = (const float*)d_in[0];
    const float* W0  = (const float*)d_in[1];
    const float* b0  = (const float*)d_in[2];
    const float* Wq  = (const float*)d_in[3];
    const float* bq  = (const float*)d_in[4];
    const float* Wk  = (const float*)d_in[5];
    const float* bk  = (const float*)d_in[6];
    const float* Wv  = (const float*)d_in[7];
    const float* bv  = (const float*)d_in[8];
    const float* W1  = (const float*)d_in[9];
    const float* b1  = (const float*)d_in[10];
    const float* pek = (const float*)d_in[11];
    const float* pev = (const float*)d_in[12];
    float* out = (float*)d_out;

    const size_t NTD = (size_t)NB * TT * DD;        // 1,048,576 elements
    f16* q16     = (f16*)d_ws;                      // 2 MB
    char* wimg   = (char*)(q16 + NTD);              // 5 x 32KB
    char* kimg   = wimg + 5 * 32768;                // 128 x 16KB = 2 MB
    char* vimg   = kimg + (size_t)128 * 16384;      // 2 MB
    char* pekimg = vimg + (size_t)128 * 16384;      // 32 KB
    char* pevimg = pekimg + 32768;                  // 32 KB

    const int SMEM_QKV  = 114688;
    const int SMEM_ATTN = 74176;                    // 2 blocks/CU
    hipFuncSetAttribute(reinterpret_cast<const void*>(fused_qkv),
                        hipFuncAttributeMaxDynamicSharedMemorySize, SMEM_QKV);
    hipFuncSetAttribute(reinterpret_cast<const void*>(attn_all),
                        hipFuncAttributeMaxDynamicSharedMemorySize, SMEM_ATTN);

    hipLaunchKernelGGL(prep_all, dim3(7), dim3(256), 0, stream,
                       W0, Wq, Wk, Wv, W1, pek, pev, wimg, pekimg, pevimg);
    hipLaunchKernelGGL(fused_qkv, dim3(256), dim3(256), SMEM_QKV, stream,
                       x, wimg, b0, bq, bk, bv, q16, kimg, vimg);
    hipLaunchKernelGGL(attn_all, dim3(512), dim3(256), SMEM_ATTN, stream,
                       q16, kimg, pekimg, vimg, pevimg, pek, pev,
                       wimg + 4 * 32768, b1, out);
}